// Round 1
// baseline (259.850 us; speedup 1.0000x reference)
//
#include <hip/hip_runtime.h>
#include <math.h>

#define T_SEQ 34
#define NTOK 14
#define NE (T_SEQ * NTOK) // 476

__global__ __launch_bounds__(256) void micro_fused_kernel(
    const int* __restrict__ idx,
    const float* __restrict__ tok_emb,
    const float* __restrict__ s_amp, const float* __restrict__ s_phase,
    const float* __restrict__ s_slope, const float* __restrict__ s_offset,
    const float* __restrict__ pc_slope, const float* __restrict__ pc_int,
    const float* __restrict__ z_hi, const float* __restrict__ spec,
    const float* __restrict__ q_w, const float* __restrict__ v_w,
    const float* __restrict__ out_A, const float* __restrict__ out_B,
    const float* __restrict__ q_phase,
    const float* __restrict__ ln1_w, const float* __restrict__ ln2_w,
    const float* __restrict__ lnf_w,
    const float* __restrict__ fc1_w, const float* __restrict__ fc1_b,
    const float* __restrict__ fc2_w, const float* __restrict__ fc2_b,
    const float* __restrict__ head_w,
    float* __restrict__ out, int N)
{
    // (tok,t)-indexed tables: entry e = t*14 + tok, 5 floats each
    __shared__ float Xs[NE * 5];  // raw x (residual)
    __shared__ float Qs[NE * 5];  // rotated q
    __shared__ float Ks[NE * 5];  // k pre-scaled by 1/sqrt(5)
    __shared__ float Vs[NE * 5];
    __shared__ float Ws[5 * NTOK]; // head_w.T @ tok_emb.T, [d][v]
    __shared__ float M5s[25];      // out_A @ out_B, [i][j]
    __shared__ float ln2s[5], lnfs[5], fc1ws[10], fc1bs[2], fc2ws[10], fc2bs[5];
    __shared__ int toks[9 * T_SEQ]; // tokens for the (<=9) rows this block touches

    const int tid = threadIdx.x;

    // ---- per-block table build (476 entries, ~2 per thread) ----
    {
        const float amp = s_amp[0], ph = s_phase[0], slp = s_slope[0], off = s_offset[0];
        const float pcs = pc_slope[0], pci = pc_int[0];
        const float cph = cosf(q_phase[0]), sph = sinf(q_phase[0]);
        const float invs5 = 0.44721359549995793f; // 1/sqrt(HEAD_DIM)
        for (int e = tid; e < NE; e += 256) {
            int t = e / NTOK, tk = e - t * NTOK;
            float px, py, pz;
            if (t == 33)      { px = 0.f;     py = 0.f;     pz = 0.f; }
            else if (t == 32) { px = z_hi[0]; py = z_hi[1]; pz = z_hi[2]; }
            else if (t == 10) { px = spec[0]; py = spec[1]; pz = spec[2]; }
            else if (t == 21) { px = spec[3]; py = spec[4]; pz = spec[5]; }
            else {
                int i = (t < 10) ? t : (t < 21 ? t - 11 : t - 22);
                float fi = (float)i;
                float ang = 0.62831853071795864769f * fi + ph; // 2*pi*i/10 + phase
                float mlt = 1.f + pci + pcs * fi;
                px = amp * cosf(ang) * mlt;
                py = amp * sinf(ang) * mlt;
                pz = (slp * fi + off) * mlt;
            }
            float x0 = tok_emb[tk * 2], x1 = tok_emb[tk * 2 + 1];
            float ssum = x0 * x0 + x1 * x1 + px * px + py * py + pz * pz;
            float r = rsqrtf(ssum * 0.2f + 1e-5f);
            float h0 = x0 * r * ln1_w[0], h1 = x1 * r * ln1_w[1];
            float h2 = px * r * ln1_w[2], h3 = py * r * ln1_w[3], h4 = pz * r * ln1_w[4];
            // q = q_w(5x3) @ h[2:5]
            float q0 = q_w[0]  * h2 + q_w[1]  * h3 + q_w[2]  * h4;
            float q1 = q_w[3]  * h2 + q_w[4]  * h3 + q_w[5]  * h4;
            float q2 = q_w[6]  * h2 + q_w[7]  * h3 + q_w[8]  * h4;
            float q3 = q_w[9]  * h2 + q_w[10] * h3 + q_w[11] * h4;
            float q4 = q_w[12] * h2 + q_w[13] * h3 + q_w[14] * h4;
            float* X = &Xs[e * 5]; X[0] = x0; X[1] = x1; X[2] = px; X[3] = py; X[4] = pz;
            float* K = &Ks[e * 5];
            K[0] = q0 * invs5; K[1] = q1 * invs5; K[2] = q2 * invs5;
            K[3] = q3 * invs5; K[4] = q4 * invs5;
            float* Q = &Qs[e * 5];
            Q[0] = q0 * cph - q1 * sph; Q[1] = q0 * sph + q1 * cph;
            Q[2] = q2 * cph - q3 * sph; Q[3] = q2 * sph + q3 * cph; Q[4] = q4;
            float* V = &Vs[e * 5];
            V[0] = v_w[0] * h0 + v_w[1] * h1; V[1] = v_w[2] * h0 + v_w[3] * h1;
            V[2] = v_w[4] * h0 + v_w[5] * h1; V[3] = v_w[6] * h0 + v_w[7] * h1;
            V[4] = v_w[8] * h0 + v_w[9] * h1;
        }
    }
    if (tid < 70) { // W[d][v] = sum_c head_w[c*5+d] * tok_emb[v*2+c]
        int d = tid / NTOK, v = tid - d * NTOK;
        Ws[tid] = head_w[d] * tok_emb[v * 2] + head_w[5 + d] * tok_emb[v * 2 + 1];
    }
    if (tid < 25) { // M5[i][j] = sum_c out_A[i*2+c] * out_B[c*5+j]
        int i = tid / 5, j = tid - i * 5;
        M5s[tid] = out_A[i * 2] * out_B[j] + out_A[i * 2 + 1] * out_B[5 + j];
    }
    if (tid < 5)  { ln2s[tid] = ln2_w[tid]; lnfs[tid] = lnf_w[tid]; fc2bs[tid] = fc2_b[tid]; }
    if (tid < 10) { fc1ws[tid] = fc1_w[tid]; fc2ws[tid] = fc2_w[tid]; }
    if (tid < 2)  { fc1bs[tid] = fc1_b[tid]; }

    // ---- stage this block's row tokens into LDS ----
    const int blockStart = blockIdx.x * 256;
    const int b0 = blockStart / T_SEQ;
    int lastLin = blockStart + 255; if (lastLin >= N) lastLin = N - 1;
    const int nrows = lastLin / T_SEQ - b0 + 1; // <= 9
    for (int i = tid; i < nrows * T_SEQ; i += 256)
        toks[i] = idx[b0 * T_SEQ + i];

    __syncthreads();

    const int lin = blockStart + tid;
    if (lin >= N) return;
    const int b = lin / T_SEQ;
    const int t = lin - b * T_SEQ;
    const int* row = &toks[(b - b0) * T_SEQ];

    const int et = (t * NTOK + row[t]) * 5;
    float qv[5], xv[5];
#pragma unroll
    for (int d = 0; d < 5; ++d) { qv[d] = Qs[et + d]; xv[d] = Xs[et + d]; }

    // ---- causal online-softmax attention over s <= t ----
    float m = -1e30f, l = 0.f;
    float a0 = 0.f, a1 = 0.f, a2 = 0.f, a3 = 0.f, a4 = 0.f;
    int base = 0;
    for (int s = 0; s <= t; ++s, base += 5 * NTOK) {
        int o = base + row[s] * 5;
        float sc = qv[0] * Ks[o]     + qv[1] * Ks[o + 1] + qv[2] * Ks[o + 2]
                 + qv[3] * Ks[o + 3] + qv[4] * Ks[o + 4];
        float nm = fmaxf(m, sc);
        float al = __expf(m - nm);
        float p  = __expf(sc - nm);
        l = l * al + p;
        a0 = a0 * al + p * Vs[o];     a1 = a1 * al + p * Vs[o + 1];
        a2 = a2 * al + p * Vs[o + 2]; a3 = a3 * al + p * Vs[o + 3];
        a4 = a4 * al + p * Vs[o + 4];
        m = nm;
    }
    float il = 1.f / l;
    float o0 = a0 * il, o1 = a1 * il, o2 = a2 * il, o3 = a3 * il, o4 = a4 * il;

    // ---- residual + FFN + final RMS + logits ----
    float y[5];
#pragma unroll
    for (int j = 0; j < 5; ++j)
        y[j] = xv[j] + o0 * M5s[j] + o1 * M5s[5 + j] + o2 * M5s[10 + j]
             + o3 * M5s[15 + j] + o4 * M5s[20 + j];

    float s2 = y[0]*y[0] + y[1]*y[1] + y[2]*y[2] + y[3]*y[3] + y[4]*y[4];
    float r2 = rsqrtf(s2 * 0.2f + 1e-5f);
    float hh[5];
#pragma unroll
    for (int j = 0; j < 5; ++j) hh[j] = y[j] * r2 * ln2s[j];

    float u0 = fc1bs[0], u1 = fc1bs[1];
#pragma unroll
    for (int j = 0; j < 5; ++j) { u0 += hh[j] * fc1ws[j]; u1 += hh[j] * fc1ws[5 + j]; }
    float g0 = 0.5f * u0 * (1.f + erff(u0 * 0.70710678118654752f));
    float g1 = 0.5f * u1 * (1.f + erff(u1 * 0.70710678118654752f));

    float y2[5]; float s3 = 0.f;
#pragma unroll
    for (int j = 0; j < 5; ++j) {
        y2[j] = y[j] + g0 * fc2ws[j * 2] + g1 * fc2ws[j * 2 + 1] + fc2bs[j];
        s3 += y2[j] * y2[j];
    }
    float r3 = rsqrtf(s3 * 0.2f + 1e-5f);
    float z[5];
#pragma unroll
    for (int j = 0; j < 5; ++j) z[j] = y2[j] * r3 * lnfs[j];

    float res[14];
#pragma unroll
    for (int v = 0; v < 14; ++v)
        res[v] = z[0] * Ws[v] + z[1] * Ws[14 + v] + z[2] * Ws[28 + v]
               + z[3] * Ws[42 + v] + z[4] * Ws[56 + v];

    float2* op = (float2*)(out + (size_t)lin * 14); // 56B stride -> 8B aligned
#pragma unroll
    for (int v = 0; v < 7; ++v) op[v] = make_float2(res[2 * v], res[2 * v + 1]);
}

extern "C" void kernel_launch(void* const* d_in, const int* in_sizes, int n_in,
                              void* d_out, int out_size, void* d_ws, size_t ws_size,
                              hipStream_t stream) {
    const int N = in_sizes[0]; // B*T = 2,228,224
    const int grid = (N + 255) / 256;
    micro_fused_kernel<<<grid, 256, 0, stream>>>(
        (const int*)d_in[0],
        (const float*)d_in[1], (const float*)d_in[2], (const float*)d_in[3],
        (const float*)d_in[4], (const float*)d_in[5], (const float*)d_in[6],
        (const float*)d_in[7], (const float*)d_in[8], (const float*)d_in[9],
        (const float*)d_in[10], (const float*)d_in[11], (const float*)d_in[12],
        (const float*)d_in[13], (const float*)d_in[14], (const float*)d_in[15],
        (const float*)d_in[16], (const float*)d_in[17], (const float*)d_in[18],
        (const float*)d_in[19], (const float*)d_in[20], (const float*)d_in[21],
        (const float*)d_in[22],
        (float*)d_out, N);
}

// Round 2
// 229.092 us; speedup vs baseline: 1.1343x; 1.1343x over previous
//
#include <hip/hip_runtime.h>
#include <math.h>

#define T_SEQ 34
#define NTOK 14
#define NE (T_SEQ * NTOK) // 476

__global__ __launch_bounds__(256) void micro_fused_kernel(
    const int* __restrict__ idx,
    const float* __restrict__ tok_emb,
    const float* __restrict__ s_amp, const float* __restrict__ s_phase,
    const float* __restrict__ s_slope, const float* __restrict__ s_offset,
    const float* __restrict__ pc_slope, const float* __restrict__ pc_int,
    const float* __restrict__ z_hi, const float* __restrict__ spec,
    const float* __restrict__ q_w, const float* __restrict__ v_w,
    const float* __restrict__ out_A, const float* __restrict__ out_B,
    const float* __restrict__ q_phase,
    const float* __restrict__ ln1_w, const float* __restrict__ ln2_w,
    const float* __restrict__ lnf_w,
    const float* __restrict__ fc1_w, const float* __restrict__ fc1_b,
    const float* __restrict__ fc2_w, const float* __restrict__ fc2_b,
    const float* __restrict__ head_w,
    float* __restrict__ out, int N)
{
    // H8[e] = [h2,h3,h4,h0,h1,-,-,-]  (RMS-normed h, padded to 8-float stride)
    __shared__ float H8[NE * 8];
    // C3[e] = q_w^T @ q_rot(e) * invsqrt(5)  (3-vec, padded to 4)
    __shared__ float C3[NE * 4];
    __shared__ float PosT[T_SEQ * 3];   // pos vector per t
    __shared__ float TE[NTOK * 2];      // tok_emb
    __shared__ float PMs[10];           // PM[j][c] = sum_i M5[i][j]*v_w[i*2+c]
    __shared__ float Ws[5 * NTOK];      // head_w.T @ tok_emb.T, [d][v]
    __shared__ float ln2s[5], lnfs[5], fc1ws[10], fc1bs[2], fc2ws[10], fc2bs[5];
    __shared__ int toks[9 * T_SEQ];

    const int tid = threadIdx.x;

    // ---- per-block table build ----
    {
        const float amp = s_amp[0], ph = s_phase[0], slp = s_slope[0], off = s_offset[0];
        const float pcs = pc_slope[0], pci = pc_int[0];
        const float cph = cosf(q_phase[0]), sph = sinf(q_phase[0]);
        const float invs5 = 0.44721359549995793f; // 1/sqrt(HEAD_DIM)
        for (int e = tid; e < NE; e += 256) {
            int t = e / NTOK, tk = e - t * NTOK;
            float px, py, pz;
            if (t == 33)      { px = 0.f;     py = 0.f;     pz = 0.f; }
            else if (t == 32) { px = z_hi[0]; py = z_hi[1]; pz = z_hi[2]; }
            else if (t == 10) { px = spec[0]; py = spec[1]; pz = spec[2]; }
            else if (t == 21) { px = spec[3]; py = spec[4]; pz = spec[5]; }
            else {
                int i = (t < 10) ? t : (t < 21 ? t - 11 : t - 22);
                float fi = (float)i;
                float ang = 0.62831853071795864769f * fi + ph;
                float mlt = 1.f + pci + pcs * fi;
                px = amp * cosf(ang) * mlt;
                py = amp * sinf(ang) * mlt;
                pz = (slp * fi + off) * mlt;
            }
            if (tk == 0) { PosT[t*3] = px; PosT[t*3+1] = py; PosT[t*3+2] = pz; }
            float x0 = tok_emb[tk * 2], x1 = tok_emb[tk * 2 + 1];
            float ssum = x0*x0 + x1*x1 + px*px + py*py + pz*pz;
            float r = rsqrtf(ssum * 0.2f + 1e-5f);
            float h0 = x0 * r * ln1_w[0], h1 = x1 * r * ln1_w[1];
            float h2 = px * r * ln1_w[2], h3 = py * r * ln1_w[3], h4 = pz * r * ln1_w[4];
            float q0 = q_w[0]  * h2 + q_w[1]  * h3 + q_w[2]  * h4;
            float q1 = q_w[3]  * h2 + q_w[4]  * h3 + q_w[5]  * h4;
            float q2 = q_w[6]  * h2 + q_w[7]  * h3 + q_w[8]  * h4;
            float q3 = q_w[9]  * h2 + q_w[10] * h3 + q_w[11] * h4;
            float q4 = q_w[12] * h2 + q_w[13] * h3 + q_w[14] * h4;
            float r0 = q0 * cph - q1 * sph, r1 = q0 * sph + q1 * cph;
            float r2c = q2 * cph - q3 * sph, r3 = q2 * sph + q3 * cph;
            // C3[p] = sum_j qrot_j * q_w[j*3+p] * invs5
            float c0 = (r0*q_w[0] + r1*q_w[3] + r2c*q_w[6] + r3*q_w[9]  + q4*q_w[12]) * invs5;
            float c1 = (r0*q_w[1] + r1*q_w[4] + r2c*q_w[7] + r3*q_w[10] + q4*q_w[13]) * invs5;
            float c2 = (r0*q_w[2] + r1*q_w[5] + r2c*q_w[8] + r3*q_w[11] + q4*q_w[14]) * invs5;
            float* H = &H8[e * 8];
            H[0] = h2; H[1] = h3; H[2] = h4; H[3] = h0; H[4] = h1;
            float* C = &C3[e * 4];
            C[0] = c0; C[1] = c1; C[2] = c2; C[3] = 0.f;
        }
    }
    if (tid < 28) TE[tid] = tok_emb[tid];
    if (tid < 70) { // W[d][v] = sum_c head_w[c*5+d] * tok_emb[v*2+c]
        int d = tid / NTOK, v = tid - d * NTOK;
        Ws[tid] = head_w[d] * tok_emb[v * 2] + head_w[5 + d] * tok_emb[v * 2 + 1];
    }
    if (tid < 10) { // PM[j][c] = sum_i (out_A[i]@out_B[:,j]) * v_w[i*2+c]
        int j = tid >> 1, c = tid & 1;
        float acc = 0.f;
        for (int i = 0; i < 5; ++i) {
            float m5 = out_A[i*2] * out_B[j] + out_A[i*2+1] * out_B[5 + j];
            acc += m5 * v_w[i*2 + c];
        }
        PMs[tid] = acc;
    }
    if (tid < 5)  { ln2s[tid] = ln2_w[tid]; lnfs[tid] = lnf_w[tid]; fc2bs[tid] = fc2_b[tid]; }
    if (tid < 10) { fc1ws[tid] = fc1_w[tid]; fc2ws[tid] = fc2_w[tid]; }
    if (tid < 2)  { fc1bs[tid] = fc1_b[tid]; }

    // ---- stage this block's row tokens ----
    const int blockStart = blockIdx.x * 256;
    const int b0 = blockStart / T_SEQ;
    int lastLin = blockStart + 255; if (lastLin >= N) lastLin = N - 1;
    const int nrows = lastLin / T_SEQ - b0 + 1; // <= 9
    for (int i = tid; i < nrows * T_SEQ; i += 256)
        toks[i] = idx[b0 * T_SEQ + i];

    __syncthreads();

    const int lin = blockStart + tid;
    if (lin >= N) return;
    const int b = lin / T_SEQ;
    const int t = lin - b * T_SEQ;
    const int rowBase = (b - b0) * T_SEQ;

    const int tokt = toks[rowBase + t];
    const float4 c3 = *(const float4*)&C3[(t * NTOK + tokt) * 4];
    const float xv0 = TE[tokt * 2], xv1 = TE[tokt * 2 + 1];
    const float xv2 = PosT[t*3], xv3 = PosT[t*3+1], xv4 = PosT[t*3+2];

    // ---- causal attention, direct exp (scores bounded), rank-2 V accumulate ----
    float l = 0.f, a0 = 0.f, a1 = 0.f;
    for (int s = 0; s <= t; ++s) {
        int o = (s * NTOK + toks[rowBase + s]) * 8;
        float4 h = *(const float4*)&H8[o];   // h2,h3,h4,h0
        float h1 = H8[o + 4];
        float sc = fmaf(c3.x, h.x, fmaf(c3.y, h.y, c3.z * h.z));
        float p = __expf(sc);
        l += p;
        a0 = fmaf(p, h.w, a0);
        a1 = fmaf(p, h1, a1);
    }
    const float il = 1.f / l;
    a0 *= il; a1 *= il;

    // ---- residual via PM, FFN, final RMS, logits ----
    float y[5];
#pragma unroll
    for (int j = 0; j < 5; ++j)
        y[j] = (j == 0 ? xv0 : j == 1 ? xv1 : j == 2 ? xv2 : j == 3 ? xv3 : xv4)
             + PMs[j*2] * a0 + PMs[j*2+1] * a1;

    float s2 = y[0]*y[0] + y[1]*y[1] + y[2]*y[2] + y[3]*y[3] + y[4]*y[4];
    float r2 = rsqrtf(s2 * 0.2f + 1e-5f);
    float hh[5];
#pragma unroll
    for (int j = 0; j < 5; ++j) hh[j] = y[j] * r2 * ln2s[j];

    float u0 = fc1bs[0], u1 = fc1bs[1];
#pragma unroll
    for (int j = 0; j < 5; ++j) { u0 += hh[j] * fc1ws[j]; u1 += hh[j] * fc1ws[5 + j]; }
    float g0 = 0.5f * u0 * (1.f + erff(u0 * 0.70710678118654752f));
    float g1 = 0.5f * u1 * (1.f + erff(u1 * 0.70710678118654752f));

    float y2[5]; float s3 = 0.f;
#pragma unroll
    for (int j = 0; j < 5; ++j) {
        y2[j] = y[j] + g0 * fc2ws[j * 2] + g1 * fc2ws[j * 2 + 1] + fc2bs[j];
        s3 += y2[j] * y2[j];
    }
    float r3 = rsqrtf(s3 * 0.2f + 1e-5f);
    float z[5];
#pragma unroll
    for (int j = 0; j < 5; ++j) z[j] = y2[j] * r3 * lnfs[j];

    float res[14];
#pragma unroll
    for (int v = 0; v < 14; ++v)
        res[v] = z[0] * Ws[v] + z[1] * Ws[14 + v] + z[2] * Ws[28 + v]
               + z[3] * Ws[42 + v] + z[4] * Ws[56 + v];

    float2* op = (float2*)(out + (size_t)lin * 14);
#pragma unroll
    for (int v = 0; v < 7; ++v) op[v] = make_float2(res[2 * v], res[2 * v + 1]);
}

extern "C" void kernel_launch(void* const* d_in, const int* in_sizes, int n_in,
                              void* d_out, int out_size, void* d_ws, size_t ws_size,
                              hipStream_t stream) {
    const int N = in_sizes[0]; // B*T
    const int grid = (N + 255) / 256;
    micro_fused_kernel<<<grid, 256, 0, stream>>>(
        (const int*)d_in[0],
        (const float*)d_in[1], (const float*)d_in[2], (const float*)d_in[3],
        (const float*)d_in[4], (const float*)d_in[5], (const float*)d_in[6],
        (const float*)d_in[7], (const float*)d_in[8], (const float*)d_in[9],
        (const float*)d_in[10], (const float*)d_in[11], (const float*)d_in[12],
        (const float*)d_in[13], (const float*)d_in[14], (const float*)d_in[15],
        (const float*)d_in[16], (const float*)d_in[17], (const float*)d_in[18],
        (const float*)d_in[19], (const float*)d_in[20], (const float*)d_in[21],
        (const float*)d_in[22],
        (float*)d_out, N);
}